// Round 1
// baseline (554.431 us; speedup 1.0000x reference)
//
#include <hip/hip_runtime.h>
#include <hip/hip_bf16.h>

typedef unsigned short u16;
typedef __attribute__((ext_vector_type(8))) short bf16x8;
typedef __attribute__((ext_vector_type(4))) float f32x4;
typedef __attribute__((ext_vector_type(8))) unsigned short u16x8;

#define MFMA16(a, b, c) __builtin_amdgcn_mfma_f32_16x16x32_bf16((a), (b), (c), 0, 0, 0)

__device__ __forceinline__ u16 f2b(float f) {
  union { float f; unsigned u; } c; c.f = f;
  unsigned u = c.u;
  u += 0x7FFFu + ((u >> 16) & 1u);   // RNE
  return (u16)(u >> 16);
}

__device__ __forceinline__ void gload_lds16(const u16* g, u16* l) {
  __builtin_amdgcn_global_load_lds(
      (__attribute__((address_space(1))) void*)(g),
      (__attribute__((address_space(3))) void*)(l),
      16, 0, 0);
}

// ---------------- f32 -> bf16 convert (x) ----------------
__global__ __launch_bounds__(256) void convert_f32_bf16(const float* __restrict__ in,
                                                        u16* __restrict__ out) {
  int i = (blockIdx.x * 256 + threadIdx.x) * 8;   // grid sized exactly
  float4 a = *(const float4*)&in[i];
  float4 b = *(const float4*)&in[i + 4];
  u16x8 o;
  o[0] = f2b(a.x); o[1] = f2b(a.y); o[2] = f2b(a.z); o[3] = f2b(a.w);
  o[4] = f2b(b.x); o[5] = f2b(b.y); o[6] = f2b(b.z); o[7] = f2b(b.w);
  *(u16x8*)&out[i] = o;
}

// ---------------- transpose + convert weights: Wt[n][k] = bf16(W[k][n]) ----------------
__global__ __launch_bounds__(256) void transpose_convert_w(
    const float* __restrict__ W0, const float* __restrict__ W1,
    const float* __restrict__ W2, const float* __restrict__ W3,
    u16* __restrict__ Wts) {
  __shared__ float t[32][33];
  int z = blockIdx.z;
  const float* W = (z == 0) ? W0 : (z == 1) ? W1 : (z == 2) ? W2 : W3;
  u16* Wt = Wts + (size_t)z * 1048576;
  int n0 = blockIdx.x * 32, k0 = blockIdx.y * 32;
  int tx = threadIdx.x, ty = threadIdx.y;
#pragma unroll
  for (int i = 0; i < 32; i += 8)
    t[ty + i][tx] = W[(size_t)(k0 + ty + i) * 1024 + n0 + tx];
  __syncthreads();
#pragma unroll
  for (int i = 0; i < 32; i += 8)
    Wt[(size_t)(n0 + ty + i) * 1024 + k0 + tx] = f2b(t[tx][ty + i]);
}

// ---------------- per-(b,h) V transpose: Vt[d][s] = V[s][d] (64 x 2048 per block) -----
__global__ __launch_bounds__(256) void transpose_v(const u16* __restrict__ V,
                                                   u16* __restrict__ Vt) {
  __shared__ u16 t[32][33];
  int bh = blockIdx.z;
  int s0 = blockIdx.x * 32, d0 = blockIdx.y * 32;
  const u16* Vb = V + (size_t)bh * 131072;
  u16* Vtb = Vt + (size_t)bh * 131072;
  int tx = threadIdx.x, ty = threadIdx.y;
#pragma unroll
  for (int i = 0; i < 32; i += 8)
    t[ty + i][tx] = Vb[(s0 + ty + i) * 64 + d0 + tx];
  __syncthreads();
#pragma unroll
  for (int i = 0; i < 32; i += 8)
    Vtb[(d0 + ty + i) * 2048 + s0 + tx] = t[tx][ty + i];
}

// ---------------- bf16 GEMM: out = A(8192x1024) * W(1024x1024) + bias ----------------
// Wt is n-major (transposed). m97 structure: 128x128 tile, BK=32, 4 waves 2x2,
// global_load_lds width 16, 16x16x32 MFMA, 4x4 acc per wave.
template <bool F32OUT>
__global__ __launch_bounds__(256) void gemm_kernel(
    const u16* __restrict__ A, const u16* __restrict__ Wt0,
    const float* __restrict__ bias0, const float* __restrict__ bias1,
    const float* __restrict__ bias2,
    u16* __restrict__ outB, float* __restrict__ outF) {
  int z = blockIdx.z;
  const u16* Wt = Wt0 + (size_t)z * 1048576;
  const float* bias = (z == 0) ? bias0 : (z == 1) ? bias1 : bias2;
  u16* outb = outB + (size_t)z * 8388608;

  __shared__ u16 Alds[128 * 32];
  __shared__ u16 Blds[128 * 32];
  int tid = threadIdx.x;
  int lane = tid & 63, w = tid >> 6;
  int brow = blockIdx.x * 128;
  int bcol = blockIdx.y * 128;
  int wr = (w >> 1) * 64, wc = (w & 1) * 64;
  int r = lane & 15, half = lane >> 4;

  f32x4 acc[4][4] = {};
  int f0 = (w * 2 + 0) * 512 + lane * 8;   // flat bf16 index in the 128x32 tile
  int f1 = (w * 2 + 1) * 512 + lane * 8;
  const u16* Abase = A + (size_t)brow * 1024;
  const u16* Bbase = Wt + (size_t)bcol * 1024;

  for (int k0 = 0; k0 < 1024; k0 += 32) {
    gload_lds16(Abase + (size_t)(f0 >> 5) * 1024 + k0 + (f0 & 31), &Alds[(w * 2 + 0) * 512]);
    gload_lds16(Abase + (size_t)(f1 >> 5) * 1024 + k0 + (f1 & 31), &Alds[(w * 2 + 1) * 512]);
    gload_lds16(Bbase + (size_t)(f0 >> 5) * 1024 + k0 + (f0 & 31), &Blds[(w * 2 + 0) * 512]);
    gload_lds16(Bbase + (size_t)(f1 >> 5) * 1024 + k0 + (f1 & 31), &Blds[(w * 2 + 1) * 512]);
    __syncthreads();
    bf16x8 af[4], bf[4];
#pragma unroll
    for (int m = 0; m < 4; ++m)
      af[m] = *(const bf16x8*)&Alds[(wr + m * 16 + r) * 32 + half * 8];
#pragma unroll
    for (int n = 0; n < 4; ++n)
      bf[n] = *(const bf16x8*)&Blds[(wc + n * 16 + r) * 32 + half * 8];
#pragma unroll
    for (int m = 0; m < 4; ++m)
#pragma unroll
      for (int n = 0; n < 4; ++n)
        acc[m][n] = MFMA16(af[m], bf[n], acc[m][n]);
    __syncthreads();
  }
#pragma unroll
  for (int m = 0; m < 4; ++m) {
    int rowb = brow + wr + m * 16 + half * 4;
#pragma unroll
    for (int n = 0; n < 4; ++n) {
      int col = bcol + wc + n * 16 + r;
      float bv = bias[col];
#pragma unroll
      for (int j = 0; j < 4; ++j) {
        float v = acc[m][n][j] + bv;
        size_t idx = (size_t)(rowb + j) * 1024 + col;
        if (F32OUT) outF[idx] = v;
        else        outb[idx] = f2b(v);
      }
    }
  }
}

// ---------------- causal flash attention per (b,h): N=2048, D=64 ----------------
// wg = 256 thr (4 waves), 64 q-rows per wg (16 per wave), 32-key tiles.
__global__ __launch_bounds__(256) void attn_kernel(
    const u16* __restrict__ Q, const u16* __restrict__ K,
    const u16* __restrict__ Vt, u16* __restrict__ Z) {
  int bh = blockIdx.y;
  int q0 = blockIdx.x * 64;
  int tid = threadIdx.x;
  int lane = tid & 63, w = tid >> 6;
  int r = lane & 15, half = lane >> 4;
  const u16* Qb = Q + (size_t)bh * 131072;
  const u16* Kb = K + (size_t)bh * 131072;
  const u16* Vb = Vt + (size_t)bh * 131072;   // d-major: Vt[d][s]
  u16* Zb = Z + (size_t)bh * 131072;
  __shared__ u16 Plds[4][512];               // per-wave 16x32 P tile

  int qrow = q0 + w * 16;
  bf16x8 qf0 = *(const bf16x8*)&Qb[(qrow + r) * 64 + half * 8];
  bf16x8 qf1 = *(const bf16x8*)&Qb[(qrow + r) * 64 + 32 + half * 8];
  f32x4 om[4] = {};
  float m_run[4], l_run[4];
#pragma unroll
  for (int j = 0; j < 4; ++j) { m_run[j] = -1e30f; l_run[j] = 0.f; }

  int nkt = q0 / 32 + 2;                     // uniform across wg (masking covers extra)
  for (int kt = 0; kt < nkt; ++kt) {
    int kb = kt * 32;
    f32x4 s0 = {0.f, 0.f, 0.f, 0.f}, s1 = {0.f, 0.f, 0.f, 0.f};
    {
      bf16x8 kf00 = *(const bf16x8*)&Kb[(kb + r) * 64 + half * 8];
      bf16x8 kf01 = *(const bf16x8*)&Kb[(kb + r) * 64 + 32 + half * 8];
      bf16x8 kf10 = *(const bf16x8*)&Kb[(kb + 16 + r) * 64 + half * 8];
      bf16x8 kf11 = *(const bf16x8*)&Kb[(kb + 16 + r) * 64 + 32 + half * 8];
      s0 = MFMA16(qf0, kf00, s0);
      s0 = MFMA16(qf1, kf01, s0);
      s1 = MFMA16(qf0, kf10, s1);
      s1 = MFMA16(qf1, kf11, s1);
    }
    int ki0 = kb + r, ki1 = kb + 16 + r;
    int qi = qrow + half * 4;
    float p0[4], p1[4];
#pragma unroll
    for (int j = 0; j < 4; ++j) {
      float sv0 = s0[j] * 0.125f;
      float sv1 = s1[j] * 0.125f;
      if (ki0 > qi + j) sv0 = -1e30f;
      if (ki1 > qi + j) sv1 = -1e30f;
      float pm = fmaxf(sv0, sv1);
#pragma unroll
      for (int d = 1; d < 16; d <<= 1) pm = fmaxf(pm, __shfl_xor(pm, d, 64));
      float nm = fmaxf(m_run[j], pm);
      float corr = __expf(m_run[j] - nm);
      m_run[j] = nm;
      float e0 = __expf(sv0 - nm);
      float e1 = __expf(sv1 - nm);
      p0[j] = e0; p1[j] = e1;
      float rs = e0 + e1;
#pragma unroll
      for (int d = 1; d < 16; d <<= 1) rs += __shfl_xor(rs, d, 64);
      l_run[j] = l_run[j] * corr + rs;
#pragma unroll
      for (int f = 0; f < 4; ++f) om[f][j] *= corr;
    }
    // P (C-layout) -> LDS row-major 16x32 so PV A-frags are contiguous b128 reads
#pragma unroll
    for (int j = 0; j < 4; ++j) {
      Plds[w][(half * 4 + j) * 32 + r]      = f2b(p0[j]);
      Plds[w][(half * 4 + j) * 32 + 16 + r] = f2b(p1[j]);
    }
    __syncthreads();
    bf16x8 pa = *(const bf16x8*)&Plds[w][r * 32 + half * 8];
#pragma unroll
    for (int f = 0; f < 4; ++f) {
      bf16x8 vf = *(const bf16x8*)&Vb[(f * 16 + r) * 2048 + kb + half * 8];
      om[f] = MFMA16(pa, vf, om[f]);
    }
    __syncthreads();
  }
#pragma unroll
  for (int j = 0; j < 4; ++j) {
    float inv = 1.0f / l_run[j];
    int q = qrow + half * 4 + j;
#pragma unroll
    for (int f = 0; f < 4; ++f)
      Zb[(size_t)q * 64 + f * 16 + r] = f2b(om[f][j] * inv);
  }
}

extern "C" void kernel_launch(void* const* d_in, const int* in_sizes, int n_in,
                              void* d_out, int out_size, void* d_ws, size_t ws_size,
                              hipStream_t stream) {
  (void)in_sizes; (void)n_in; (void)out_size; (void)ws_size;
  const float* x  = (const float*)d_in[0];
  const float* Wq = (const float*)d_in[1];
  const float* bq = (const float*)d_in[2];
  const float* Wk = (const float*)d_in[3];
  const float* bk = (const float*)d_in[4];
  const float* Wv = (const float*)d_in[5];
  const float* bv = (const float*)d_in[6];
  const float* Wo = (const float*)d_in[7];
  const float* bo = (const float*)d_in[8];
  float* out = (float*)d_out;

  char* ws = (char*)d_ws;
  u16* xb  = (u16*)(ws);                  // 16 MB, reused as Z after attention
  u16* Wts = (u16*)(ws + 16777216);       // 4 x 2 MB (q,k,v,o; n-major bf16)
  u16* Qb  = (u16*)(ws + 25165824);       // 16 MB
  u16* Kb  = (u16*)(ws + 41943040);       // 16 MB
  u16* Vb  = (u16*)(ws + 58720256);       // 16 MB
  u16* Vtb = (u16*)(ws + 75497472);       // 16 MB  (total 92 MB)

  convert_f32_bf16<<<4096, 256, 0, stream>>>(x, xb);
  {
    dim3 g(32, 32, 4), b(32, 8);
    transpose_convert_w<<<g, b, 0, stream>>>(Wq, Wk, Wv, Wo, Wts);
  }
  {
    dim3 g(64, 8, 3), b(256);
    gemm_kernel<false><<<g, b, 0, stream>>>(xb, Wts, bq, bk, bv, Qb, nullptr);
  }
  {
    dim3 g(64, 2, 64), b(32, 8);
    transpose_v<<<g, b, 0, stream>>>(Vb, Vtb);
  }
  {
    dim3 g(32, 64), b(256);
    attn_kernel<<<g, b, 0, stream>>>(Qb, Kb, Vtb, xb /* Z */);
  }
  {
    dim3 g(64, 8, 1), b(256);
    gemm_kernel<true><<<g, b, 0, stream>>>(xb, Wts + 3 * 1048576, bo, bo, bo, Qb, out);
  }
}

// Round 2
// 343.770 us; speedup vs baseline: 1.6128x; 1.6128x over previous
//
#include <hip/hip_runtime.h>
#include <hip/hip_bf16.h>

typedef unsigned short u16;
typedef __attribute__((ext_vector_type(8))) short bf16x8;
typedef __attribute__((ext_vector_type(4))) float f32x4;
typedef __attribute__((ext_vector_type(8))) unsigned short u16x8;

#define MFMA16(a, b, c) __builtin_amdgcn_mfma_f32_16x16x32_bf16((a), (b), (c), 0, 0, 0)

__device__ __forceinline__ u16 f2b(float f) {
  union { float f; unsigned u; } c; c.f = f;
  unsigned u = c.u;
  u += 0x7FFFu + ((u >> 16) & 1u);   // RNE
  return (u16)(u >> 16);
}

__device__ __forceinline__ void gload_lds16(const u16* g, u16* l) {
  __builtin_amdgcn_global_load_lds(
      (__attribute__((address_space(1))) void*)(g),
      (__attribute__((address_space(3))) void*)(l),
      16, 0, 0);
}

// ---------------- f32 -> bf16 convert (x) ----------------
__global__ __launch_bounds__(256) void convert_f32_bf16(const float* __restrict__ in,
                                                        u16* __restrict__ out) {
  int i = (blockIdx.x * 256 + threadIdx.x) * 8;   // grid sized exactly
  float4 a = *(const float4*)&in[i];
  float4 b = *(const float4*)&in[i + 4];
  u16x8 o;
  o[0] = f2b(a.x); o[1] = f2b(a.y); o[2] = f2b(a.z); o[3] = f2b(a.w);
  o[4] = f2b(b.x); o[5] = f2b(b.y); o[6] = f2b(b.z); o[7] = f2b(b.w);
  *(u16x8*)&out[i] = o;
}

// ---------------- transpose + convert weights: Wt[n][k] = bf16(W[k][n]) ----------------
__global__ __launch_bounds__(256) void transpose_convert_w(
    const float* __restrict__ W0, const float* __restrict__ W1,
    const float* __restrict__ W2, const float* __restrict__ W3,
    u16* __restrict__ Wts) {
  __shared__ float t[32][33];
  int z = blockIdx.z;
  const float* W = (z == 0) ? W0 : (z == 1) ? W1 : (z == 2) ? W2 : W3;
  u16* Wt = Wts + (size_t)z * 1048576;
  int n0 = blockIdx.x * 32, k0 = blockIdx.y * 32;
  int tx = threadIdx.x, ty = threadIdx.y;
#pragma unroll
  for (int i = 0; i < 32; i += 8)
    t[ty + i][tx] = W[(size_t)(k0 + ty + i) * 1024 + n0 + tx];
  __syncthreads();
#pragma unroll
  for (int i = 0; i < 32; i += 8)
    Wt[(size_t)(n0 + ty + i) * 1024 + k0 + tx] = f2b(t[tx][ty + i]);
}

// ---------------- per-(b,h) V transpose: Vt[d][s] = V[s][d] (64 x 2048 per block) -----
__global__ __launch_bounds__(256) void transpose_v(const u16* __restrict__ V,
                                                   u16* __restrict__ Vt) {
  __shared__ u16 t[32][33];
  int bh = blockIdx.z;
  int s0 = blockIdx.x * 32, d0 = blockIdx.y * 32;
  const u16* Vb = V + (size_t)bh * 131072;
  u16* Vtb = Vt + (size_t)bh * 131072;
  int tx = threadIdx.x, ty = threadIdx.y;
#pragma unroll
  for (int i = 0; i < 32; i += 8)
    t[ty + i][tx] = Vb[(s0 + ty + i) * 64 + d0 + tx];
  __syncthreads();
#pragma unroll
  for (int i = 0; i < 32; i += 8)
    Vtb[(d0 + ty + i) * 2048 + s0 + tx] = t[tx][ty + i];
}

// ---------------- bf16 GEMM: out = A(8192x1024) * W(1024x1024) + bias ----------------
// Wt is n-major (transposed). m97 structure: 128x128 tile, BK=32, 4 waves 2x2,
// global_load_lds width 16, 16x16x32 MFMA, 4x4 acc per wave.
// For z==0 (Q projection) the 1/sqrt(DH)=0.125 attention scale is folded in.
template <bool F32OUT>
__global__ __launch_bounds__(256) void gemm_kernel(
    const u16* __restrict__ A, const u16* __restrict__ Wt0,
    const float* __restrict__ bias0, const float* __restrict__ bias1,
    const float* __restrict__ bias2,
    u16* __restrict__ outB, float* __restrict__ outF) {
  int z = blockIdx.z;
  const u16* Wt = Wt0 + (size_t)z * 1048576;
  const float* bias = (z == 0) ? bias0 : (z == 1) ? bias1 : bias2;
  u16* outb = outB + (size_t)z * 8388608;
  float oscale = (!F32OUT && z == 0) ? 0.125f : 1.0f;

  __shared__ u16 Alds[128 * 32];
  __shared__ u16 Blds[128 * 32];
  int tid = threadIdx.x;
  int lane = tid & 63, w = tid >> 6;
  int brow = blockIdx.x * 128;
  int bcol = blockIdx.y * 128;
  int wr = (w >> 1) * 64, wc = (w & 1) * 64;
  int r = lane & 15, half = lane >> 4;

  f32x4 acc[4][4] = {};
  int f0 = (w * 2 + 0) * 512 + lane * 8;   // flat bf16 index in the 128x32 tile
  int f1 = (w * 2 + 1) * 512 + lane * 8;
  const u16* Abase = A + (size_t)brow * 1024;
  const u16* Bbase = Wt + (size_t)bcol * 1024;

  for (int k0 = 0; k0 < 1024; k0 += 32) {
    gload_lds16(Abase + (size_t)(f0 >> 5) * 1024 + k0 + (f0 & 31), &Alds[(w * 2 + 0) * 512]);
    gload_lds16(Abase + (size_t)(f1 >> 5) * 1024 + k0 + (f1 & 31), &Alds[(w * 2 + 1) * 512]);
    gload_lds16(Bbase + (size_t)(f0 >> 5) * 1024 + k0 + (f0 & 31), &Blds[(w * 2 + 0) * 512]);
    gload_lds16(Bbase + (size_t)(f1 >> 5) * 1024 + k0 + (f1 & 31), &Blds[(w * 2 + 1) * 512]);
    __syncthreads();
    bf16x8 af[4], bf[4];
#pragma unroll
    for (int m = 0; m < 4; ++m)
      af[m] = *(const bf16x8*)&Alds[(wr + m * 16 + r) * 32 + half * 8];
#pragma unroll
    for (int n = 0; n < 4; ++n)
      bf[n] = *(const bf16x8*)&Blds[(wc + n * 16 + r) * 32 + half * 8];
#pragma unroll
    for (int m = 0; m < 4; ++m)
#pragma unroll
      for (int n = 0; n < 4; ++n)
        acc[m][n] = MFMA16(af[m], bf[n], acc[m][n]);
    __syncthreads();
  }
#pragma unroll
  for (int m = 0; m < 4; ++m) {
    int rowb = brow + wr + m * 16 + half * 4;
#pragma unroll
    for (int n = 0; n < 4; ++n) {
      int col = bcol + wc + n * 16 + r;
      float bv = bias[col];
#pragma unroll
      for (int j = 0; j < 4; ++j) {
        float v = (acc[m][n][j] + bv) * oscale;
        size_t idx = (size_t)(rowb + j) * 1024 + col;
        if (F32OUT) outF[idx] = v;
        else        outb[idx] = f2b(v);
      }
    }
  }
}

// ---------------- causal flash attention per (b,h): N=2048, D=64 ----------------
// Swapped-operand structure: S^T = MFMA(K, Q) so each lane owns ONE q-row
// (col = lane&15) and 16 k-values. K fragment rows are permuted so the lane's
// 16 P values are exactly an x32 MFMA B-fragment (k = c*32 + half*8 + e):
// softmax is lane-local (+2 shuffles), P feeds PV straight from registers.
// No LDS, no barriers. O^T = Vt x P^T accumulated per d-fragment.
// Q-scale (0.125) is pre-folded into Q by the projection GEMM.
__device__ __forceinline__ void attn_strip(
    const u16* __restrict__ Qb, const u16* __restrict__ Kb,
    const u16* __restrict__ Vtb, u16* __restrict__ Zb,
    int qrow, int ntiles, int r, int half) {
  const bf16x8 qf0 = *(const bf16x8*)&Qb[(qrow + r) * 64 + half * 8];
  const bf16x8 qf1 = *(const bf16x8*)&Qb[(qrow + r) * 64 + 32 + half * 8];
  const int q = qrow + r;
  f32x4 om[4] = {};
  float m_run = -1e30f, l_run = 0.f;

  for (int kt = 0; kt < ntiles; ++kt) {
    const int kb = kt * 64;
    f32x4 sT[2][2];
#pragma unroll
    for (int c = 0; c < 2; ++c)
#pragma unroll
      for (int t = 0; t < 2; ++t) {
        // permuted K row so lane's S^T values form the PV B-fragment layout
        const int krow = kb + c * 32 + (r >> 2) * 8 + t * 4 + (r & 3);
        const bf16x8 kf0 = *(const bf16x8*)&Kb[krow * 64 + half * 8];
        const bf16x8 kf1 = *(const bf16x8*)&Kb[krow * 64 + 32 + half * 8];
        f32x4 zacc = {};
        zacc = MFMA16(kf0, qf0, zacc);
        zacc = MFMA16(kf1, qf1, zacc);
        sT[c][t] = zacc;
      }
    if (kt == ntiles - 1) {   // causal mask, wave-uniform branch (last tile only)
#pragma unroll
      for (int c = 0; c < 2; ++c)
#pragma unroll
        for (int t = 0; t < 2; ++t)
#pragma unroll
          for (int j = 0; j < 4; ++j)
            if (kb + c * 32 + half * 8 + t * 4 + j > q) sT[c][t][j] = -1e30f;
    }
    // lane-local online softmax (this lane's q-row)
    float mloc = sT[0][0][0];
#pragma unroll
    for (int c = 0; c < 2; ++c)
#pragma unroll
      for (int t = 0; t < 2; ++t)
#pragma unroll
        for (int j = 0; j < 4; ++j) mloc = fmaxf(mloc, sT[c][t][j]);
    mloc = fmaxf(mloc, __shfl_xor(mloc, 16));
    mloc = fmaxf(mloc, __shfl_xor(mloc, 32));
    const float nm = fmaxf(m_run, mloc);
    const float corr = __expf(m_run - nm);
    m_run = nm;
    float lloc = 0.f;
    u16x8 pu[2];
#pragma unroll
    for (int c = 0; c < 2; ++c)
#pragma unroll
      for (int t = 0; t < 2; ++t)
#pragma unroll
        for (int j = 0; j < 4; ++j) {
          const float e = __expf(sT[c][t][j] - nm);
          lloc += e;
          pu[c][t * 4 + j] = f2b(e);
        }
    lloc += __shfl_xor(lloc, 16);
    lloc += __shfl_xor(lloc, 32);
    l_run = l_run * corr + lloc;
#pragma unroll
    for (int f = 0; f < 4; ++f)
#pragma unroll
      for (int j = 0; j < 4; ++j) om[f][j] *= corr;
    // PV: om (O^T chunk) += Vt-frag x P^T-frag, all from registers
#pragma unroll
    for (int c = 0; c < 2; ++c) {
      const bf16x8 pb = __builtin_bit_cast(bf16x8, pu[c]);
#pragma unroll
      for (int f = 0; f < 4; ++f) {
        const bf16x8 vf = *(const bf16x8*)&Vtb[(f * 16 + r) * 2048 + kb + c * 32 + half * 8];
        om[f] = MFMA16(vf, pb, om[f]);
      }
    }
  }
  const float inv = 1.0f / l_run;
#pragma unroll
  for (int f = 0; f < 4; ++f) {
    ushort4 st;
    st.x = f2b(om[f][0] * inv);
    st.y = f2b(om[f][1] * inv);
    st.z = f2b(om[f][2] * inv);
    st.w = f2b(om[f][3] * inv);
    *(ushort4*)&Zb[(size_t)q * 64 + f * 16 + half * 4] = st;
  }
}

__global__ __launch_bounds__(256) void attn_kernel(
    const u16* __restrict__ Q, const u16* __restrict__ K,
    const u16* __restrict__ Vt, u16* __restrict__ Z) {
  const int bh = blockIdx.y;
  const int x = blockIdx.x;           // pairs q-block x with q-block 31-x (balance)
  const int lane = threadIdx.x & 63;
  const int w = threadIdx.x >> 6;
  const int r = lane & 15, half = lane >> 4;
  const u16* Qb = Q + (size_t)bh * 131072;
  const u16* Kb = K + (size_t)bh * 131072;
  const u16* Vb = Vt + (size_t)bh * 131072;
  u16* Zb = Z + (size_t)bh * 131072;
  attn_strip(Qb, Kb, Vb, Zb, x * 64 + w * 16, x + 1, r, half);
  attn_strip(Qb, Kb, Vb, Zb, (31 - x) * 64 + w * 16, 32 - x, r, half);
}

extern "C" void kernel_launch(void* const* d_in, const int* in_sizes, int n_in,
                              void* d_out, int out_size, void* d_ws, size_t ws_size,
                              hipStream_t stream) {
  (void)in_sizes; (void)n_in; (void)out_size; (void)ws_size;
  const float* x  = (const float*)d_in[0];
  const float* Wq = (const float*)d_in[1];
  const float* bq = (const float*)d_in[2];
  const float* Wk = (const float*)d_in[3];
  const float* bk = (const float*)d_in[4];
  const float* Wv = (const float*)d_in[5];
  const float* bv = (const float*)d_in[6];
  const float* Wo = (const float*)d_in[7];
  const float* bo = (const float*)d_in[8];
  float* out = (float*)d_out;

  char* ws = (char*)d_ws;
  u16* xb  = (u16*)(ws);                  // 16 MB, reused as Z after attention
  u16* Wts = (u16*)(ws + 16777216);       // 4 x 2 MB (q,k,v,o; n-major bf16)
  u16* Qb  = (u16*)(ws + 25165824);       // 16 MB
  u16* Kb  = (u16*)(ws + 41943040);       // 16 MB
  u16* Vb  = (u16*)(ws + 58720256);       // 16 MB
  u16* Vtb = (u16*)(ws + 75497472);       // 16 MB  (total 92 MB)

  convert_f32_bf16<<<4096, 256, 0, stream>>>(x, xb);
  {
    dim3 g(32, 32, 4), b(32, 8);
    transpose_convert_w<<<g, b, 0, stream>>>(Wq, Wk, Wv, Wo, Wts);
  }
  {
    dim3 g(64, 8, 3), b(256);
    gemm_kernel<false><<<g, b, 0, stream>>>(xb, Wts, bq, bk, bv, Qb, nullptr);
  }
  {
    dim3 g(64, 2, 64), b(32, 8);
    transpose_v<<<g, b, 0, stream>>>(Vb, Vtb);
  }
  {
    dim3 g(16, 64), b(256);
    attn_kernel<<<g, b, 0, stream>>>(Qb, Kb, Vtb, xb /* Z */);
  }
  {
    dim3 g(64, 8, 1), b(256);
    gemm_kernel<true><<<g, b, 0, stream>>>(xb, Wts + 3 * 1048576, bo, bo, bo, Qb, out);
  }
}

// Round 4
// 188.545 us; speedup vs baseline: 2.9406x; 1.8233x over previous
//
#include <hip/hip_runtime.h>
#include <hip/hip_bf16.h>

typedef unsigned short u16;
typedef __attribute__((ext_vector_type(8))) short bf16x8;
typedef __attribute__((ext_vector_type(4))) float f32x4;
typedef __attribute__((ext_vector_type(8))) unsigned short u16x8;

#define MFMA16(a, b, c) __builtin_amdgcn_mfma_f32_16x16x32_bf16((a), (b), (c), 0, 0, 0)

// LDS XOR swizzle for 128-byte rows: colbyte ^= SWZB(row). Gives uniform
// 8-lanes-per-16B-slot spread for both the permuted-K reads and V reads.
#define SWZB(row) ((((row) & 3) | ((((row) >> 3) & 1) << 2)) << 4)

__device__ __forceinline__ u16 f2b(float f) {
  union { float f; unsigned u; } c; c.f = f;
  unsigned u = c.u;
  u += 0x7FFFu + ((u >> 16) & 1u);   // RNE
  return (u16)(u >> 16);
}

__device__ __forceinline__ void gload_lds16(const u16* g, u16* l) {
  __builtin_amdgcn_global_load_lds(
      (__attribute__((address_space(1))) void*)(g),
      (__attribute__((address_space(3))) void*)(l),
      16, 0, 0);
}

// ---------------- f32 -> bf16 convert (x) ----------------
__global__ __launch_bounds__(256) void convert_f32_bf16(const float* __restrict__ in,
                                                        u16* __restrict__ out) {
  int i = (blockIdx.x * 256 + threadIdx.x) * 8;   // grid sized exactly
  float4 a = *(const float4*)&in[i];
  float4 b = *(const float4*)&in[i + 4];
  u16x8 o;
  o[0] = f2b(a.x); o[1] = f2b(a.y); o[2] = f2b(a.z); o[3] = f2b(a.w);
  o[4] = f2b(b.x); o[5] = f2b(b.y); o[6] = f2b(b.z); o[7] = f2b(b.w);
  *(u16x8*)&out[i] = o;
}

// ---------------- transpose + convert weights: Wt[n][k] = bf16(W[k][n]) ----------------
__global__ __launch_bounds__(256) void transpose_convert_w(
    const float* __restrict__ W0, const float* __restrict__ W1,
    const float* __restrict__ W2, const float* __restrict__ W3,
    u16* __restrict__ Wts) {
  __shared__ float t[32][33];
  int z = blockIdx.z;
  const float* W = (z == 0) ? W0 : (z == 1) ? W1 : (z == 2) ? W2 : W3;
  u16* Wt = Wts + (size_t)z * 1048576;
  int n0 = blockIdx.x * 32, k0 = blockIdx.y * 32;
  int tx = threadIdx.x, ty = threadIdx.y;
#pragma unroll
  for (int i = 0; i < 32; i += 8)
    t[ty + i][tx] = W[(size_t)(k0 + ty + i) * 1024 + n0 + tx];
  __syncthreads();
#pragma unroll
  for (int i = 0; i < 32; i += 8)
    Wt[(size_t)(n0 + ty + i) * 1024 + k0 + tx] = f2b(t[tx][ty + i]);
}

// ---------------- per-(b,h) V transpose: Vt[d][s] = V[s][d] (64 x 2048 per block) -----
// Operates on the contiguous-slab (reshape) head layout — verified correct in R2.
__global__ __launch_bounds__(256) void transpose_v(const u16* __restrict__ V,
                                                   u16* __restrict__ Vt) {
  __shared__ u16 t[32][33];
  int bh = blockIdx.z;
  int s0 = blockIdx.x * 32, d0 = blockIdx.y * 32;
  const u16* Vb = V + (size_t)bh * 131072;
  u16* Vtb = Vt + (size_t)bh * 131072;
  int tx = threadIdx.x, ty = threadIdx.y;
#pragma unroll
  for (int i = 0; i < 32; i += 8)
    t[ty + i][tx] = Vb[(s0 + ty + i) * 64 + d0 + tx];
  __syncthreads();
#pragma unroll
  for (int i = 0; i < 32; i += 8)
    Vtb[(d0 + ty + i) * 2048 + s0 + tx] = t[tx][ty + i];
}

// ---------------- bf16 GEMM: out = A(8192x1024) * W(1024x1024) + bias ----------------
// Wt is n-major (transposed). m97 structure: 128x128 tile, BK=32, 4 waves 2x2,
// global_load_lds width 16, 16x16x32 MFMA, 4x4 acc per wave.
// z==0 (Q proj, bf16 out): folds the 1/sqrt(DH)=0.125 attention scale.
template <bool F32OUT>
__global__ __launch_bounds__(256) void gemm_kernel(
    const u16* __restrict__ A, const u16* __restrict__ Wt0,
    const float* __restrict__ bias0, const float* __restrict__ bias1,
    const float* __restrict__ bias2,
    u16* __restrict__ outB, float* __restrict__ outF) {
  int z = blockIdx.z;
  const u16* Wt = Wt0 + (size_t)z * 1048576;
  const float* bias = (z == 0) ? bias0 : (z == 1) ? bias1 : bias2;
  u16* outb = outB + (size_t)z * 8388608;
  float oscale = (!F32OUT && z == 0) ? 0.125f : 1.0f;

  __shared__ u16 Alds[128 * 32];
  __shared__ u16 Blds[128 * 32];
  int tid = threadIdx.x;
  int lane = tid & 63, w = tid >> 6;
  int brow = blockIdx.x * 128;
  int bcol = blockIdx.y * 128;
  int wr = (w >> 1) * 64, wc = (w & 1) * 64;
  int r = lane & 15, half = lane >> 4;

  f32x4 acc[4][4] = {};
  int f0 = (w * 2 + 0) * 512 + lane * 8;   // flat bf16 index in the 128x32 tile
  int f1 = (w * 2 + 1) * 512 + lane * 8;
  const u16* Abase = A + (size_t)brow * 1024;
  const u16* Bbase = Wt + (size_t)bcol * 1024;

  for (int k0 = 0; k0 < 1024; k0 += 32) {
    gload_lds16(Abase + (size_t)(f0 >> 5) * 1024 + k0 + (f0 & 31), &Alds[(w * 2 + 0) * 512]);
    gload_lds16(Abase + (size_t)(f1 >> 5) * 1024 + k0 + (f1 & 31), &Alds[(w * 2 + 1) * 512]);
    gload_lds16(Bbase + (size_t)(f0 >> 5) * 1024 + k0 + (f0 & 31), &Blds[(w * 2 + 0) * 512]);
    gload_lds16(Bbase + (size_t)(f1 >> 5) * 1024 + k0 + (f1 & 31), &Blds[(w * 2 + 1) * 512]);
    __syncthreads();
    bf16x8 af[4], bf[4];
#pragma unroll
    for (int m = 0; m < 4; ++m)
      af[m] = *(const bf16x8*)&Alds[(wr + m * 16 + r) * 32 + half * 8];
#pragma unroll
    for (int n = 0; n < 4; ++n)
      bf[n] = *(const bf16x8*)&Blds[(wc + n * 16 + r) * 32 + half * 8];
#pragma unroll
    for (int m = 0; m < 4; ++m)
#pragma unroll
      for (int n = 0; n < 4; ++n)
        acc[m][n] = MFMA16(af[m], bf[n], acc[m][n]);
    __syncthreads();
  }
#pragma unroll
  for (int m = 0; m < 4; ++m) {
    int rowb = brow + wr + m * 16 + half * 4;
#pragma unroll
    for (int n = 0; n < 4; ++n) {
      int col = bcol + wc + n * 16 + r;
      float bv = bias[col];
#pragma unroll
      for (int j = 0; j < 4; ++j) {
        float v = (acc[m][n][j] + bv) * oscale;
        size_t idx = (size_t)(rowb + j) * 1024 + col;
        if (F32OUT) outF[idx] = v;
        else        outb[idx] = f2b(v);
      }
    }
  }
}

// ---------------- causal flash attention per (b,h): N=2048, D=64 ----------------
// Swapped-operand structure: S^T = MFMA(K, Q), lane owns one q-row; permuted K
// rows make the lane's 16 P values exactly the PV B-fragment; softmax is
// lane-local + 2 shuffles. K/V tiles cooperatively staged into double-buffered
// XOR-swizzled LDS via async global_load_lds (prefetch t+1 during compute of t).
__device__ __forceinline__ void attn_stage(
    const u16* __restrict__ Kb, const u16* __restrict__ Vtb,
    u16* Kl, u16* Vl, int kb, int tid) {
  const int row0 = tid >> 3;            // 0..31
  const int cb0 = (tid & 7) << 4;       // byte col within 128B row
  const int row1 = row0 + 32;
  gload_lds16(Kb + (size_t)(kb + row0) * 64 + ((cb0 ^ SWZB(row0)) >> 1), Kl + tid * 8);
  gload_lds16(Kb + (size_t)(kb + row1) * 64 + ((cb0 ^ SWZB(row1)) >> 1), Kl + 2048 + tid * 8);
  gload_lds16(Vtb + (size_t)row0 * 2048 + kb + ((cb0 ^ SWZB(row0)) >> 1), Vl + tid * 8);
  gload_lds16(Vtb + (size_t)row1 * 2048 + kb + ((cb0 ^ SWZB(row1)) >> 1), Vl + 2048 + tid * 8);
}

__device__ __forceinline__ void attn_strip(
    const u16* __restrict__ Qb, const u16* __restrict__ Kb,
    const u16* __restrict__ Vtb, u16* __restrict__ Zb,
    u16 (*Kl)[4096], u16 (*Vl)[4096], int qrow, int nt, int tid) {
  const int lane = tid & 63;
  const int r = lane & 15, half = lane >> 4;
  const bf16x8 qf0 = *(const bf16x8*)&Qb[(qrow + r) * 64 + half * 8];
  const bf16x8 qf1 = *(const bf16x8*)&Qb[(qrow + r) * 64 + 32 + half * 8];
  const int q = qrow + r;
  f32x4 om[4] = {};
  float m_run = -1e30f, l_run = 0.f;

  __syncthreads();                       // seal previous readers of buf0
  attn_stage(Kb, Vtb, Kl[0], Vl[0], 0, tid);
  int cur = 0;

  for (int kt = 0; kt < nt; ++kt) {
    const int kb = kt * 64;
    __syncthreads();                     // drains staging (vmcnt0) + makes visible
    if (kt + 1 < nt) attn_stage(Kb, Vtb, Kl[cur ^ 1], Vl[cur ^ 1], kb + 64, tid);
    const char* Kc = (const char*)Kl[cur];
    const char* Vc = (const char*)Vl[cur];

    f32x4 sT[2][2];
#pragma unroll
    for (int c = 0; c < 2; ++c)
#pragma unroll
      for (int t = 0; t < 2; ++t) {
        const int krow = c * 32 + ((r >> 2) << 3) + t * 4 + (r & 3);
        const char* krp = Kc + krow * 128;
        const bf16x8 kf0 = *(const bf16x8*)(krp + ((half * 16) ^ SWZB(krow)));
        const bf16x8 kf1 = *(const bf16x8*)(krp + ((64 + half * 16) ^ SWZB(krow)));
        f32x4 zacc = {};
        zacc = MFMA16(kf0, qf0, zacc);
        zacc = MFMA16(kf1, qf1, zacc);
        sT[c][t] = zacc;
      }
    if (kt == nt - 1) {   // causal mask, last tile only
#pragma unroll
      for (int c = 0; c < 2; ++c)
#pragma unroll
        for (int t = 0; t < 2; ++t)
#pragma unroll
          for (int j = 0; j < 4; ++j)
            if (kb + c * 32 + half * 8 + t * 4 + j > q) sT[c][t][j] = -1e30f;
    }
    // lane-local online softmax
    float mloc = sT[0][0][0];
#pragma unroll
    for (int c = 0; c < 2; ++c)
#pragma unroll
      for (int t = 0; t < 2; ++t)
#pragma unroll
        for (int j = 0; j < 4; ++j) mloc = fmaxf(mloc, sT[c][t][j]);
    mloc = fmaxf(mloc, __shfl_xor(mloc, 16));
    mloc = fmaxf(mloc, __shfl_xor(mloc, 32));
    const float nm = fmaxf(m_run, mloc);
    const float corr = __expf(m_run - nm);
    m_run = nm;
    float lloc = 0.f;
    u16x8 pu[2];
#pragma unroll
    for (int c = 0; c < 2; ++c)
#pragma unroll
      for (int t = 0; t < 2; ++t)
#pragma unroll
        for (int j = 0; j < 4; ++j) {
          const float e = __expf(sT[c][t][j] - nm);
          lloc += e;
          pu[c][t * 4 + j] = f2b(e);
        }
    lloc += __shfl_xor(lloc, 16);
    lloc += __shfl_xor(lloc, 32);
    l_run = l_run * corr + lloc;
#pragma unroll
    for (int f = 0; f < 4; ++f)
#pragma unroll
      for (int j = 0; j < 4; ++j) om[f][j] *= corr;
    // PV from LDS V fragments
#pragma unroll
    for (int c = 0; c < 2; ++c) {
      const bf16x8 pb = __builtin_bit_cast(bf16x8, pu[c]);
#pragma unroll
      for (int f = 0; f < 4; ++f) {
        const int vrow = f * 16 + r;
        const bf16x8 vf = *(const bf16x8*)(Vc + vrow * 128 + ((c * 64 + half * 16) ^ SWZB(vrow)));
        om[f] = MFMA16(vf, pb, om[f]);
      }
    }
    cur ^= 1;
  }
  const float inv = 1.0f / l_run;
#pragma unroll
  for (int f = 0; f < 4; ++f) {
    ushort4 st;
    st.x = f2b(om[f][0] * inv);
    st.y = f2b(om[f][1] * inv);
    st.z = f2b(om[f][2] * inv);
    st.w = f2b(om[f][3] * inv);
    *(ushort4*)&Zb[(size_t)q * 64 + f * 16 + half * 4] = st;
  }
}

__global__ __launch_bounds__(256) void attn_kernel(
    const u16* __restrict__ Q, const u16* __restrict__ K,
    const u16* __restrict__ Vt, u16* __restrict__ Z) {
  __shared__ u16 Kl[2][4096];
  __shared__ u16 Vl[2][4096];
  // XCD-affinity swizzle: all 16 q-block-pairs of a head land on one XCD
  // (round-robin dispatch: xcd = linear % 8). 8 heads/XCD -> ~4MB L2 set.
  const int L = blockIdx.x;
  const int xcd = L & 7;
  const int i = L >> 3;
  const int bh = ((i >> 4) << 3) + xcd;   // heads with bh%8 == xcd
  const int x = i & 15;                   // q-block pair index
  const int tid = threadIdx.x;
  const int w = tid >> 6;
  const u16* Qb = Q + (size_t)bh * 131072;
  const u16* Kb = K + (size_t)bh * 131072;
  const u16* Vb = Vt + (size_t)bh * 131072;
  u16* Zb = Z + (size_t)bh * 131072;
  attn_strip(Qb, Kb, Vb, Zb, Kl, Vl, x * 64 + w * 16, x + 1, tid);
  attn_strip(Qb, Kb, Vb, Zb, Kl, Vl, (31 - x) * 64 + w * 16, 32 - x, tid);
}

extern "C" void kernel_launch(void* const* d_in, const int* in_sizes, int n_in,
                              void* d_out, int out_size, void* d_ws, size_t ws_size,
                              hipStream_t stream) {
  (void)in_sizes; (void)n_in; (void)out_size; (void)ws_size;
  const float* x  = (const float*)d_in[0];
  const float* Wq = (const float*)d_in[1];
  const float* bq = (const float*)d_in[2];
  const float* Wk = (const float*)d_in[3];
  const float* bk = (const float*)d_in[4];
  const float* Wv = (const float*)d_in[5];
  const float* bv = (const float*)d_in[6];
  const float* Wo = (const float*)d_in[7];
  const float* bo = (const float*)d_in[8];
  float* out = (float*)d_out;

  char* ws = (char*)d_ws;
  u16* xb  = (u16*)(ws);                  // 16 MB, reused as Z after attention
  u16* Wts = (u16*)(ws + 16777216);       // 4 x 2 MB (q,k,v,o; n-major bf16)
  u16* Qb  = (u16*)(ws + 25165824);       // 16 MB
  u16* Kb  = (u16*)(ws + 41943040);       // 16 MB
  u16* Vb  = (u16*)(ws + 58720256);       // 16 MB
  u16* Vtb = (u16*)(ws + 75497472);       // 16 MB  (total 92 MB)

  convert_f32_bf16<<<4096, 256, 0, stream>>>(x, xb);
  {
    dim3 g(32, 32, 4), b(32, 8);
    transpose_convert_w<<<g, b, 0, stream>>>(Wq, Wk, Wv, Wo, Wts);
  }
  {
    dim3 g(64, 8, 3), b(256);
    gemm_kernel<false><<<g, b, 0, stream>>>(xb, Wts, bq, bk, bv, Qb, nullptr);
  }
  {
    dim3 g(64, 2, 64), b(32, 8);
    transpose_v<<<g, b, 0, stream>>>(Vb, Vtb);
  }
  {
    dim3 g(1024), b(256);
    attn_kernel<<<g, b, 0, stream>>>(Qb, Kb, Vtb, xb /* Z */);
  }
  {
    dim3 g(64, 8, 1), b(256);
    gemm_kernel<true><<<g, b, 0, stream>>>(xb, Wts + 3 * 1048576, bo, bo, bo, Qb, out);
  }
}